// Round 6
// baseline (1064.299 us; speedup 1.0000x reference)
//
#include <hip/hip_runtime.h>
#include <stdint.h>

#define R_NODES 256
#define M_SAMP  512
#define S_STEPS 512
#define OUT_N   10

typedef uint32_t u32x2 __attribute__((ext_vector_type(2)));

// ---------------- layout detection for bool inputs ----------------
// If bools were uploaded as int32, byte (4f+1) of every element is 0.
// If uploaded as uint8, ~half those bytes are 1.  flag=1 => uint8 layout.
__global__ void detect_layout(const uint8_t* __restrict__ x, int* __restrict__ flag) {
    __shared__ int any;
    if (threadIdx.x == 0) any = 0;
    __syncthreads();
    int acc = 0;
    for (int i = 0; i < 64; ++i)
        acc |= x[(size_t)(threadIdx.x * 64 + i) * 4 + 1];
    if (acc) atomicOr(&any, 1);
    __syncthreads();
    if (threadIdx.x == 0) *flag = any ? 1 : 0;
}

// ---------------- pack x bits: one uint32 per (m,s) ----------------
__global__ void pack_x(const uint8_t* __restrict__ x, const int* __restrict__ flag,
                       uint32_t* __restrict__ xp) {
    const int stride = (*flag) ? 1 : 4;
    const int f = blockIdx.x * blockDim.x + threadIdx.x;      // element idx, M*S*32 total
    const int val = x[(size_t)f * stride];
    const uint64_t mask = __ballot(val != 0);
    const int lane = threadIdx.x & 63;
    if ((lane & 31) == 0) {
        uint32_t w = (lane & 32) ? (uint32_t)(mask >> 32) : (uint32_t)mask;
        xp[f >> 5] = w;
    }
}

// ---------------- build byte-chunk partial-sum table ----------------
// T2[(v*32 + c)*256 + col'(j)] = sum_{b in v} primes[c*8+b]*W_res[j][c*8+b]
// Column PERMUTED: col'(j) = 4*(j&63) + (j>>6), so that lane l of the main
// kernel (owning nodes l, l+64, l+128, l+192) reads one contiguous dwordx2.
__global__ void build_T2(const uint8_t* __restrict__ wres, const int* __restrict__ primes,
                         const int* __restrict__ flag, uint16_t* __restrict__ T2) {
    const int v = blockIdx.x;          // 0..255 byte value
    const int c = blockIdx.y;          // 0..31 chunk (nodes 8c..8c+7 of the mask)
    const int j = threadIdx.x;         // 0..255 node
    const int stride = (*flag) ? 1 : 4;
    int sum = 0;
#pragma unroll
    for (int b = 0; b < 8; ++b) {
        if ((v >> b) & 1) {
            const int k = c * 8 + b;
            if (wres[(size_t)(j * 256 + k) * stride]) sum += primes[k];
        }
    }
    const int colp = 4 * (j & 63) + (j >> 6);
    T2[((size_t)v * 32 + c) * 256 + colp] = (uint16_t)sum;
}

// ---------------- bit-pack the LUT: 256MB int32 -> 8MB bits ----------------
__device__ __forceinline__ uint32_t spread8(uint32_t x) {
    x = (x | (x << 12)) & 0x000F000Fu;
    x = (x | (x << 6))  & 0x03030303u;
    x = (x | (x << 3))  & 0x11111111u;
    return x;
}
__device__ __forceinline__ void pack_chunk(const int4 q, int lane, int chunk,
                                           uint32_t* __restrict__ lp32) {
    const uint64_t b0 = __ballot((q.x & 1) != 0);
    const uint64_t b1 = __ballot((q.y & 1) != 0);
    const uint64_t b2 = __ballot((q.z & 1) != 0);
    const uint64_t b3 = __ballot((q.w & 1) != 0);
    if (lane < 8) {
        const uint32_t B0 = (uint32_t)(b0 >> (8 * lane)) & 0xFF;
        const uint32_t B1 = (uint32_t)(b1 >> (8 * lane)) & 0xFF;
        const uint32_t B2 = (uint32_t)(b2 >> (8 * lane)) & 0xFF;
        const uint32_t B3 = (uint32_t)(b3 >> (8 * lane)) & 0xFF;
        const uint32_t w = spread8(B0) | (spread8(B1) << 1)
                         | (spread8(B2) << 2) | (spread8(B3) << 3);
        lp32[(size_t)chunk * 8 + lane] = w;
    }
}
__global__ void pack_lut(const int* __restrict__ lut, uint32_t* __restrict__ lp32) {
    const int lane = threadIdx.x & 63;
    const int gw = blockIdx.x * (blockDim.x >> 6) + (threadIdx.x >> 6); // global wave id, 2048
    const int4* src = (const int4*)lut;
    for (int it = 0; it < 64; ++it) {
        const int c0 = gw * 128 + it * 2;              // 262144 wave-chunks total
        const int4 q0 = src[(size_t)c0 * 64 + lane];
        const int4 q1 = src[(size_t)(c0 + 1) * 64 + lane];
        pack_chunk(q0, lane, c0, lp32);
        pack_chunk(q1, lane, c0 + 1, lp32);
    }
}

// ---------------- main reservoir scan: ONE WAVE per sample ----------------
// Lane l owns nodes {l, l+64, l+128, l+192}. The 256-bit mask is exactly 4
// __ballot results (bit l of ballot i = node l+64i) -> no LDS, no barriers.
// Round-5 lesson: the ~1000 cyc/step of barrier + LDS-exchange + cross-wave
// tail coupling was the overhead, not load serialization. 32 T2 loads per
// lane (8B each, coalesced via the build-time column permute) are forced
// into one latency round with asm; results pinned live past the waitcnt.
__global__ __launch_bounds__(64, 2) void reservoir_main(
    const uint32_t* __restrict__ xp, const uint16_t* __restrict__ T2,
    const uint64_t* __restrict__ lp, const int* __restrict__ input_nodes,
    const uint8_t* __restrict__ init_res, const int* __restrict__ flag,
    const float* __restrict__ rW, const float* __restrict__ rb,
    float* __restrict__ out)
{
    const int m = blockIdx.x;
    const int l = threadIdx.x;                 // lane 0..63
    const int stride = (*flag) ? 1 : 4;

    // input-injection slots for this lane's 4 nodes
    int slot0 = -1, slot1 = -1, slot2 = -1, slot3 = -1;
#pragma unroll
    for (int k = 0; k < 32; ++k) {
        const int n = input_nodes[k];
        if (n == l)       slot0 = k;
        if (n == l + 64)  slot1 = k;
        if (n == l + 128) slot2 = k;
        if (n == l + 192) slot3 = k;
    }
    int v0 = init_res[(size_t)(l      ) * stride] ? 1 : 0;
    int v1 = init_res[(size_t)(l +  64) * stride] ? 1 : 0;
    int v2 = init_res[(size_t)(l + 128) * stride] ? 1 : 0;
    int v3 = init_res[(size_t)(l + 192) * stride] ? 1 : 0;

    uint32_t cst[32];                          // per-chunk byte offset: c*512 + 8l
#pragma unroll
    for (int c = 0; c < 32; ++c) cst[c] = (uint32_t)(c * 512 + l * 8);

    const uint32_t* xrow = xp + m * S_STEPS;
    uint32_t xw = xrow[0];

    for (int s = 0; s < S_STEPS; ++s) {
        const uint32_t xn = xrow[(s + 1) & (S_STEPS - 1)];   // prefetch next
        if (slot0 >= 0) v0 = (xw >> slot0) & 1;
        if (slot1 >= 0) v1 = (xw >> slot1) & 1;
        if (slot2 >= 0) v2 = (xw >> slot2) & 1;
        if (slot3 >= 0) v3 = (xw >> slot3) & 1;

        const uint64_t B0 = __ballot(v0 != 0);   // mask word 0: nodes 0..63
        const uint64_t B1 = __ballot(v1 != 0);   // nodes 64..127
        const uint64_t B2 = __ballot(v2 != 0);   // nodes 128..191
        const uint64_t B3 = __ballot(v3 != 0);   // nodes 192..255
        const uint32_t H[8] = {
            (uint32_t)B0, (uint32_t)(B0 >> 32), (uint32_t)B1, (uint32_t)(B1 >> 32),
            (uint32_t)B2, (uint32_t)(B2 >> 32), (uint32_t)B3, (uint32_t)(B3 >> 32)
        };

        // 32 chunk loads, all in flight, ONE waitcnt
        u32x2 r[32];
#pragma unroll
        for (int c = 0; c < 32; ++c) {
            const uint32_t bc = (H[c >> 2] >> (8 * (c & 3))) & 0xFFu;
            const uint32_t off = (bc << 14) + cst[c];
            asm volatile("global_load_dwordx2 %0, %1, %2"
                         : "=v"(r[c]) : "v"(off), "s"(T2) : "memory");
        }
        asm volatile("s_waitcnt vmcnt(0)" ::: "memory");
#pragma unroll
        for (int c = 0; c < 32; ++c) asm volatile("" : "+v"(r[c]));  // pin uses after wait

        // packed-u16 partial sums in groups of 4 (max 4*12952=51808 < 2^16)
        uint32_t idx0 = 0, idx1 = 0, idx2 = 0, idx3 = 0;
#pragma unroll
        for (int g = 0; g < 8; ++g) {
            const uint32_t px = r[4 * g].x + r[4 * g + 1].x + r[4 * g + 2].x + r[4 * g + 3].x;
            const uint32_t py = r[4 * g].y + r[4 * g + 1].y + r[4 * g + 2].y + r[4 * g + 3].y;
            idx0 += px & 0xFFFFu; idx1 += px >> 16;
            idx2 += py & 0xFFFFu; idx3 += py >> 16;
        }

        // 4 independent gathers (compiler pipelines the waits per-ballot)
        const uint64_t w0 = lp[(size_t)(l      ) * 4096 + (idx0 >> 6)];
        const uint64_t w1 = lp[(size_t)(l +  64) * 4096 + (idx1 >> 6)];
        const uint64_t w2 = lp[(size_t)(l + 128) * 4096 + (idx2 >> 6)];
        const uint64_t w3 = lp[(size_t)(l + 192) * 4096 + (idx3 >> 6)];
        v0 = (int)((w0 >> (idx0 & 63)) & 1);
        v1 = (int)((w1 >> (idx1 & 63)) & 1);
        v2 = (int)((w2 >> (idx2 & 63)) & 1);
        v3 = (int)((w3 >> (idx3 & 63)) & 1);
        xw = xn;
    }

    // readout: out[m][o] = b[o] + sum_j v_j * W[o][j]
#pragma unroll
    for (int o = 0; o < OUT_N; ++o) {
        float c = 0.f;
        if (v0) c += rW[o * R_NODES + l];
        if (v1) c += rW[o * R_NODES + l + 64];
        if (v2) c += rW[o * R_NODES + l + 128];
        if (v3) c += rW[o * R_NODES + l + 192];
        for (int off = 32; off > 0; off >>= 1)
            c += __shfl_down(c, off, 64);
        if (l == 0) out[m * OUT_N + o] = c + rb[o];
    }
}

extern "C" void kernel_launch(void* const* d_in, const int* in_sizes, int n_in,
                              void* d_out, int out_size, void* d_ws, size_t ws_size,
                              hipStream_t stream) {
    const uint8_t* x        = (const uint8_t*)d_in[0];   // bool [M,S,D,B]
    const int* input_nodes  = (const int*)d_in[1];       // int32 [32]
    const int* lut          = (const int*)d_in[2];       // int32 [256, 2^18]
    const uint8_t* wres     = (const uint8_t*)d_in[3];   // bool [256,256]
    const int* primes       = (const int*)d_in[4];       // int32 [256]
    const uint8_t* init_res = (const uint8_t*)d_in[5];   // bool [256]
    const float* rW         = (const float*)d_in[6];     // f32 [10,256]
    const float* rb         = (const float*)d_in[7];     // f32 [10]
    float* out              = (float*)d_out;             // f32 [512,10]

    uint8_t* ws = (uint8_t*)d_ws;
    int*      flag = (int*)ws;                                        // 4 B
    uint32_t* xp   = (uint32_t*)(ws + 4096);                          // 1 MB
    uint16_t* T2   = (uint16_t*)(ws + 4096 + 1048576);                // 4 MB
    uint64_t* lp   = (uint64_t*)(ws + 4096 + 1048576 + 4194304);      // 8 MB

    detect_layout<<<1, 256, 0, stream>>>(x, flag);
    pack_x<<<(M_SAMP * S_STEPS * 32) / 256, 256, 0, stream>>>(x, flag, xp);
    build_T2<<<dim3(256, 32), 256, 0, stream>>>(wres, primes, flag, T2);
    pack_lut<<<512, 256, 0, stream>>>(lut, (uint32_t*)lp);
    reservoir_main<<<M_SAMP, 64, 0, stream>>>(xp, T2, lp, input_nodes, init_res,
                                              flag, rW, rb, out);
}

// Round 7
// 1049.929 us; speedup vs baseline: 1.0137x; 1.0137x over previous
//
#include <hip/hip_runtime.h>
#include <stdint.h>

#define R_NODES 256
#define M_SAMP  512
#define S_STEPS 512
#define OUT_N   10

typedef uint32_t u32x2 __attribute__((ext_vector_type(2)));

// ---------------- layout detection for bool inputs ----------------
// If bools were uploaded as int32, byte (4f+1) of every element is 0.
// If uploaded as uint8, ~half those bytes are 1.  flag=1 => uint8 layout.
__global__ void detect_layout(const uint8_t* __restrict__ x, int* __restrict__ flag) {
    __shared__ int any;
    if (threadIdx.x == 0) any = 0;
    __syncthreads();
    int acc = 0;
    for (int i = 0; i < 64; ++i)
        acc |= x[(size_t)(threadIdx.x * 64 + i) * 4 + 1];
    if (acc) atomicOr(&any, 1);
    __syncthreads();
    if (threadIdx.x == 0) *flag = any ? 1 : 0;
}

// ---------------- pack x bits: one uint32 per (m,s) ----------------
__global__ void pack_x(const uint8_t* __restrict__ x, const int* __restrict__ flag,
                       uint32_t* __restrict__ xp) {
    const int stride = (*flag) ? 1 : 4;
    const int f = blockIdx.x * blockDim.x + threadIdx.x;      // element idx, M*S*32 total
    const int val = x[(size_t)f * stride];
    const uint64_t mask = __ballot(val != 0);
    const int lane = threadIdx.x & 63;
    if ((lane & 31) == 0) {
        uint32_t w = (lane & 32) ? (uint32_t)(mask >> 32) : (uint32_t)mask;
        xp[f >> 5] = w;
    }
}

// ---------------- build byte-chunk partial-sum table ----------------
// T2[(v*32 + c)*256 + col'(j)] = sum_{b in v} primes[c*8+b]*W_res[j][c*8+b]
// Column PERMUTED: col'(j) = 4*(j&63) + (j>>6), so that lane l of the main
// kernel (owning nodes l, l+64, l+128, l+192) reads one contiguous dwordx2.
__global__ void build_T2(const uint8_t* __restrict__ wres, const int* __restrict__ primes,
                         const int* __restrict__ flag, uint16_t* __restrict__ T2) {
    const int v = blockIdx.x;          // 0..255 byte value
    const int c = blockIdx.y;          // 0..31 chunk (nodes 8c..8c+7 of the mask)
    const int j = threadIdx.x;         // 0..255 node
    const int stride = (*flag) ? 1 : 4;
    int sum = 0;
#pragma unroll
    for (int b = 0; b < 8; ++b) {
        if ((v >> b) & 1) {
            const int k = c * 8 + b;
            if (wres[(size_t)(j * 256 + k) * stride]) sum += primes[k];
        }
    }
    const int colp = 4 * (j & 63) + (j >> 6);
    T2[((size_t)v * 32 + c) * 256 + colp] = (uint16_t)sum;
}

// ---------------- bit-pack the LUT: 256MB int32 -> 8MB bits ----------------
__device__ __forceinline__ uint32_t spread8(uint32_t x) {
    x = (x | (x << 12)) & 0x000F000Fu;
    x = (x | (x << 6))  & 0x03030303u;
    x = (x | (x << 3))  & 0x11111111u;
    return x;
}
__device__ __forceinline__ void pack_chunk(const int4 q, int lane, int chunk,
                                           uint32_t* __restrict__ lp32) {
    const uint64_t b0 = __ballot((q.x & 1) != 0);
    const uint64_t b1 = __ballot((q.y & 1) != 0);
    const uint64_t b2 = __ballot((q.z & 1) != 0);
    const uint64_t b3 = __ballot((q.w & 1) != 0);
    if (lane < 8) {
        const uint32_t B0 = (uint32_t)(b0 >> (8 * lane)) & 0xFF;
        const uint32_t B1 = (uint32_t)(b1 >> (8 * lane)) & 0xFF;
        const uint32_t B2 = (uint32_t)(b2 >> (8 * lane)) & 0xFF;
        const uint32_t B3 = (uint32_t)(b3 >> (8 * lane)) & 0xFF;
        const uint32_t w = spread8(B0) | (spread8(B1) << 1)
                         | (spread8(B2) << 2) | (spread8(B3) << 3);
        lp32[(size_t)chunk * 8 + lane] = w;
    }
}
__global__ void pack_lut(const int* __restrict__ lut, uint32_t* __restrict__ lp32) {
    const int lane = threadIdx.x & 63;
    const int gw = blockIdx.x * (blockDim.x >> 6) + (threadIdx.x >> 6); // global wave id, 2048
    const int4* src = (const int4*)lut;
    for (int it = 0; it < 64; ++it) {
        const int c0 = gw * 128 + it * 2;              // 262144 wave-chunks total
        const int4 q0 = src[(size_t)c0 * 64 + lane];
        const int4 q1 = src[(size_t)(c0 + 1) * 64 + lane];
        pack_chunk(q0, lane, c0, lp32);
        pack_chunk(q1, lane, c0 + 1, lp32);
    }
}

// ---------------- main reservoir scan: ONE WAVE per sample ----------------
// Lane l owns nodes {l, l+64, l+128, l+192}; the 256-bit mask is 4 ballots.
// Chain per step is latency-bound: T2 round + lut gather (serial dependency).
// Round-7 changes: (1) gathers carry `sc1` (device scope) so the once-used
// lut lines are served by L3 WITHOUT evicting the 4MB T2 from per-XCD L2;
// (2) all in-loop VMEM is asm in one queue -> staged vmcnt(16) lets the
// first half of the chunk-sum overlap the second half's flight.
__global__ __launch_bounds__(64, 2) void reservoir_main(
    const uint32_t* __restrict__ xp, const uint16_t* __restrict__ T2,
    const uint64_t* __restrict__ lp, const int* __restrict__ input_nodes,
    const uint8_t* __restrict__ init_res, const int* __restrict__ flag,
    const float* __restrict__ rW, const float* __restrict__ rb,
    float* __restrict__ out)
{
    const int m = blockIdx.x;
    const int l = threadIdx.x;                 // lane 0..63
    const int stride = (*flag) ? 1 : 4;

    int slot0 = -1, slot1 = -1, slot2 = -1, slot3 = -1;
#pragma unroll
    for (int k = 0; k < 32; ++k) {
        const int n = input_nodes[k];
        if (n == l)       slot0 = k;
        if (n == l + 64)  slot1 = k;
        if (n == l + 128) slot2 = k;
        if (n == l + 192) slot3 = k;
    }
    int v0 = init_res[(size_t)(l      ) * stride] ? 1 : 0;
    int v1 = init_res[(size_t)(l +  64) * stride] ? 1 : 0;
    int v2 = init_res[(size_t)(l + 128) * stride] ? 1 : 0;
    int v3 = init_res[(size_t)(l + 192) * stride] ? 1 : 0;

    uint32_t cst[32];                          // per-chunk byte offset: c*512 + 8l
#pragma unroll
    for (int c = 0; c < 32; ++c) cst[c] = (uint32_t)(c * 512 + l * 8);
    const uint32_t grow0 = (uint32_t)(l      ) * 32768u;   // lut row byte bases
    const uint32_t grow1 = (uint32_t)(l +  64) * 32768u;
    const uint32_t grow2 = (uint32_t)(l + 128) * 32768u;
    const uint32_t grow3 = (uint32_t)(l + 192) * 32768u;

    const uint32_t* xrow = xp + m * S_STEPS;
    uint32_t xw = xrow[0];
    uint32_t xoff = 4;                         // byte offset of next x word

    for (int s = 0; s < S_STEPS; ++s) {
        // ---- prefetch next x word (first in this iteration's VMEM queue)
        uint32_t xn;
        asm volatile("global_load_dword %0, %1, %2"
                     : "=v"(xn) : "v"(xoff), "s"(xrow) : "memory");
        xoff = (xoff + 4) & (S_STEPS * 4 - 1);

        // ---- inject inputs, build mask via 4 ballots (no LDS, no barriers)
        if (slot0 >= 0) v0 = (xw >> slot0) & 1;
        if (slot1 >= 0) v1 = (xw >> slot1) & 1;
        if (slot2 >= 0) v2 = (xw >> slot2) & 1;
        if (slot3 >= 0) v3 = (xw >> slot3) & 1;
        const uint64_t B0 = __ballot(v0 != 0);
        const uint64_t B1 = __ballot(v1 != 0);
        const uint64_t B2 = __ballot(v2 != 0);
        const uint64_t B3 = __ballot(v3 != 0);
        const uint32_t H[8] = {
            (uint32_t)B0, (uint32_t)(B0 >> 32), (uint32_t)B1, (uint32_t)(B1 >> 32),
            (uint32_t)B2, (uint32_t)(B2 >> 32), (uint32_t)B3, (uint32_t)(B3 >> 32)
        };

        // ---- 32 T2 loads, all in flight (queue: xn + c0..c31)
        u32x2 r[32];
#pragma unroll
        for (int c = 0; c < 32; ++c) {
            const uint32_t bc = (H[c >> 2] >> (8 * (c & 3))) & 0xFFu;  // SALU
            const uint32_t off = (bc << 14) + cst[c];
            asm volatile("global_load_dwordx2 %0, %1, %2"
                         : "=v"(r[c]) : "v"(off), "s"(T2) : "memory");
        }

        // ---- wait for xn + chunks 0..15; sum them while 16..31 fly
        asm volatile("s_waitcnt vmcnt(16)" ::: "memory");
        asm volatile("" : "+v"(xn));
#pragma unroll
        for (int c = 0; c < 16; ++c) asm volatile("" : "+v"(r[c]));
        uint32_t px0 = 0, py0 = 0, px1 = 0, py1 = 0;   // packed u16x2 partials
#pragma unroll
        for (int g = 0; g < 2; ++g) {                   // chunks 0..7, 8..15
            uint32_t ax = 0, ay = 0;
#pragma unroll
            for (int k = 0; k < 8; ++k) { ax += r[8 * g + k].x; ay += r[8 * g + k].y; }
            if (g == 0) { px0 = ax; py0 = ay; } else { px1 = ax; py1 = ay; }
        }
        uint32_t idx0 = (px0 & 0xFFFFu) + (px1 & 0xFFFFu);
        uint32_t idx1 = (px0 >> 16)     + (px1 >> 16);
        uint32_t idx2 = (py0 & 0xFFFFu) + (py1 & 0xFFFFu);
        uint32_t idx3 = (py0 >> 16)     + (py1 >> 16);

        asm volatile("s_waitcnt vmcnt(0)" ::: "memory");
#pragma unroll
        for (int c = 16; c < 32; ++c) asm volatile("" : "+v"(r[c]));
#pragma unroll
        for (int g = 2; g < 4; ++g) {                   // chunks 16..23, 24..31
            uint32_t ax = 0, ay = 0;
#pragma unroll
            for (int k = 0; k < 8; ++k) { ax += r[8 * g + k].x; ay += r[8 * g + k].y; }
            idx0 += ax & 0xFFFFu; idx1 += ax >> 16;
            idx2 += ay & 0xFFFFu; idx3 += ay >> 16;
        }

        // ---- 4 gathers with sc1: serve from L3, don't evict T2 from L2
        const uint32_t go0 = grow0 + ((idx0 >> 3) & ~7u);
        const uint32_t go1 = grow1 + ((idx1 >> 3) & ~7u);
        const uint32_t go2 = grow2 + ((idx2 >> 3) & ~7u);
        const uint32_t go3 = grow3 + ((idx3 >> 3) & ~7u);
        uint64_t w0, w1, w2, w3;
        asm volatile("global_load_dwordx2 %0, %1, %2 sc1"
                     : "=v"(w0) : "v"(go0), "s"(lp) : "memory");
        asm volatile("global_load_dwordx2 %0, %1, %2 sc1"
                     : "=v"(w1) : "v"(go1), "s"(lp) : "memory");
        asm volatile("global_load_dwordx2 %0, %1, %2 sc1"
                     : "=v"(w2) : "v"(go2), "s"(lp) : "memory");
        asm volatile("global_load_dwordx2 %0, %1, %2 sc1"
                     : "=v"(w3) : "v"(go3), "s"(lp) : "memory");
        asm volatile("s_waitcnt vmcnt(0)" ::: "memory");
        asm volatile("" : "+v"(w0));
        asm volatile("" : "+v"(w1));
        asm volatile("" : "+v"(w2));
        asm volatile("" : "+v"(w3));
        v0 = (int)((w0 >> (idx0 & 63)) & 1);
        v1 = (int)((w1 >> (idx1 & 63)) & 1);
        v2 = (int)((w2 >> (idx2 & 63)) & 1);
        v3 = (int)((w3 >> (idx3 & 63)) & 1);
        xw = xn;
    }

    // readout: out[m][o] = b[o] + sum_j v_j * W[o][j]
#pragma unroll
    for (int o = 0; o < OUT_N; ++o) {
        float c = 0.f;
        if (v0) c += rW[o * R_NODES + l];
        if (v1) c += rW[o * R_NODES + l + 64];
        if (v2) c += rW[o * R_NODES + l + 128];
        if (v3) c += rW[o * R_NODES + l + 192];
        for (int off = 32; off > 0; off >>= 1)
            c += __shfl_down(c, off, 64);
        if (l == 0) out[m * OUT_N + o] = c + rb[o];
    }
}

extern "C" void kernel_launch(void* const* d_in, const int* in_sizes, int n_in,
                              void* d_out, int out_size, void* d_ws, size_t ws_size,
                              hipStream_t stream) {
    const uint8_t* x        = (const uint8_t*)d_in[0];   // bool [M,S,D,B]
    const int* input_nodes  = (const int*)d_in[1];       // int32 [32]
    const int* lut          = (const int*)d_in[2];       // int32 [256, 2^18]
    const uint8_t* wres     = (const uint8_t*)d_in[3];   // bool [256,256]
    const int* primes       = (const int*)d_in[4];       // int32 [256]
    const uint8_t* init_res = (const uint8_t*)d_in[5];   // bool [256]
    const float* rW         = (const float*)d_in[6];     // f32 [10,256]
    const float* rb         = (const float*)d_in[7];     // f32 [10]
    float* out              = (float*)d_out;             // f32 [512,10]

    uint8_t* ws = (uint8_t*)d_ws;
    int*      flag = (int*)ws;                                        // 4 B
    uint32_t* xp   = (uint32_t*)(ws + 4096);                          // 1 MB
    uint16_t* T2   = (uint16_t*)(ws + 4096 + 1048576);                // 4 MB
    uint64_t* lp   = (uint64_t*)(ws + 4096 + 1048576 + 4194304);      // 8 MB

    detect_layout<<<1, 256, 0, stream>>>(x, flag);
    pack_x<<<(M_SAMP * S_STEPS * 32) / 256, 256, 0, stream>>>(x, flag, xp);
    build_T2<<<dim3(256, 32), 256, 0, stream>>>(wres, primes, flag, T2);
    pack_lut<<<512, 256, 0, stream>>>(lut, (uint32_t*)lp);
    reservoir_main<<<M_SAMP, 64, 0, stream>>>(xp, T2, lp, input_nodes, init_res,
                                              flag, rW, rb, out);
}